// Round 9
// baseline (700.493 us; speedup 1.0000x reference)
//
#include <hip/hip_runtime.h>
#include <cmath>

#define NS 51
#define ND 50
#define PLANE 1048576            // 1024*1024
#define DOG_ELEMS (ND * PLANE)   // 52428800
#define WPSTRIDE 160             // padded 1-D kernel: 17 zeros | taps | zeros

typedef __attribute__((ext_vector_type(8))) _Float16 half8;

// ---------------- K0: extract normalized 1-D kernels + radii; zero fp16 zrow ----
__global__ void dog_prep(const float* __restrict__ weight,
                         float* __restrict__ wp,
                         int* __restrict__ rarr,
                         _Float16* __restrict__ zrowh, int S) {
    int i = blockIdx.x;
    int t = threadIdx.x;
    int R = (S - 1) >> 1;
    const float* row = weight + ((size_t)i * S + R) * S;   // center row of scale i
    __shared__ float sr[128];
    __shared__ float ssum;
    __shared__ int spad;
    if (t < S) sr[t] = row[t];
    for (int j = t; j < WPSTRIDE; j += blockDim.x) wp[i * WPSTRIDE + j] = 0.f;
    if (i == 0)
        for (int j = t; j < 1024; j += blockDim.x) zrowh[j] = (_Float16)0.f;
    __syncthreads();
    if (t == 0) {
        float sum = 0.f;
        for (int j = 0; j < S; ++j) sum += sr[j];
        int pad = 0;
        while (pad < R && sr[pad] == 0.f) ++pad;
        ssum = sum; spad = pad;
        rarr[i] = R - pad;
    }
    __syncthreads();
    int pad = spad;
    int r = R - pad;
    float inv = 1.f / ssum;
    for (int j = t; j <= 2 * r; j += blockDim.x)
        wp[i * WPSTRIDE + 17 + j] = sr[pad + j] * inv;
}

// ---------------- K1: horizontal blur, scale-chunked, fp16 output ---------------
__global__ __launch_bounds__(256) void dog_hblur(
        const float* __restrict__ in, _Float16* __restrict__ tmpHh,
        const float* __restrict__ wp, const int* __restrict__ rarr) {
    const int lo_t[5] = {0, 17, 28, 37, 44};
    const int hi_t[5] = {17, 28, 37, 44, 51};
    int t = threadIdx.x;
    int grp = t >> 7;
    int tl = t & 127;
    int y = (blockIdx.x << 1) | grp;
    int zc = blockIdx.y;
    __shared__ float srow[2][1144];                 // 8 phases x 143
    const float* inrow = in + ((size_t)y << 10);
    for (int e = tl; e < 286; e += 128) {           // 286 float4 = x in [-56,1088)
        int xg = (e << 2) - 56;
        float4 v = make_float4(0.f, 0.f, 0.f, 0.f);
        if (xg >= 0 && xg < 1024) v = *(const float4*)(inrow + xg);
        float vv[4] = {v.x, v.y, v.z, v.w};
        int j = e << 2;
#pragma unroll
        for (int c = 0; c < 4; ++c) {
            int jj = j + c;
            srow[grp][(jj & 7) * 143 + (jj >> 3)] = vv[c];
        }
    }
    __syncthreads();
    const float* s = srow[grp];
    for (int i = lo_t[zc]; i < hi_t[zc]; ++i) {
        int r = rarr[i];
        const float* __restrict__ w = wp + i * WPSTRIDE;
        float acc[8];
#pragma unroll
        for (int k = 0; k < 8; ++k) acc[k] = 0.f;
        int c0 = 56 - r;
        int mcount = ((2 * r + 15) >> 3) << 3;      // >= 2r+8
        for (int m = 0; m < mcount; m += 8) {
            float v[8];
#pragma unroll
            for (int j2 = 0; j2 < 8; ++j2) {
                int q = m + j2 + c0;                // uniform
                v[j2] = s[(q & 7) * 143 + tl + (q >> 3)];
            }
#pragma unroll
            for (int j2 = 0; j2 < 8; ++j2)
#pragma unroll
                for (int k = 0; k < 8; ++k)
                    acc[k] = fmaf(w[17 + m + j2 - k], v[j2], acc[k]);
        }
        _Float16* o = tmpHh + (((size_t)i) << 20) + ((size_t)y << 10) + (tl << 3);
        half8 h;
#pragma unroll
        for (int k = 0; k < 8; ++k) h[k] = (_Float16)acc[k];
        *(half8*)o = h;                             // 16B aligned store
    }
}

// ---------------- K2: fused vconv + DoG + 3x3x3 pool + epilogue -----------------
// 1-wave blocks (64 thr): 62 out cols + halo lanes, 8 out rows/thread (10-row
// window). fp16 tmpH loads (cvt to f32). Scalar row addressing (uniform cselect
// row ptr vs fp16 zero-row). XCD swizzle keeps each strip's 128 y-waves on one
// XCD. Pipelined m-loop (vA/vB) PLUS cross-scale prefetch: next scale's group-0
// loads issue BEFORE this scale's emit stores, so counted vmcnt waits never
// drain the 16 nt output stores (vmcnt retires in issue order).

#define LOADG(V, MM) do { int gyb_ = gy0 + (MM);                                  \
_Pragma("unroll")                                                                 \
    for (int j_ = 0; j_ < 8; ++j_) {                                              \
        int gy_ = gyb_ + j_;                                                      \
        const _Float16* rp_ = ((unsigned)gy_ < 1024u)                             \
                         ? (plane + ((size_t)gy_ << 10)) : zrowh;                 \
        V[j_] = (float)rp_[xi];                                                   \
    } } while (0)

#define FMAG(W, V, MM) do {                                                       \
_Pragma("unroll")                                                                 \
    for (int j_ = 0; j_ < 8; ++j_)                                                \
_Pragma("unroll")                                                                 \
        for (int k_ = 0; k_ < 10; ++k_)                                           \
            acc[k_] = fmaf((W)[17 + (MM) + j_ - k_], V[j_], acc[k_]);             \
    } while (0)

__global__ __launch_bounds__(64, 8) void dog_fused(
        const _Float16* __restrict__ tmpHh, float* __restrict__ out,
        const float* __restrict__ wp, const int* __restrict__ rarr,
        const float* __restrict__ sigmas, const float* __restrict__ thr_p,
        const _Float16* __restrict__ zrowh) {
    const int jlo_t[5] = {0, 17, 28, 37, 44};
    const int jhi_t[5] = {16, 27, 36, 43, 49};
    // ---- XCD-aware swizzle: p%8 = XCD; strip (wx,zc) pinned to one XCD.
    int p = blockIdx.x;                   // 0..11263
    int xcd = p & 7;
    int q = p >> 3;                       // 0..1407
    int c8 = q >> 7;                      // 0..10
    int ybg = q & 127;                    // 0..127 (same-XCD consecutive y-waves)
    int combo = (c8 << 3) | xcd;          // 0..87
    if (combo >= 85) return;              // pad blocks
    int wx = combo % 17;                  // 0..16
    int zc = combo / 17;                  // 0..4
    int lane = threadIdx.x & 63;
    int y0u = __builtin_amdgcn_readfirstlane(ybg << 3);   // 0..1016
    int x = wx * 62 - 1 + lane;           // -1 .. 1054
    int xi = min(max(x, 0), 1023);
    bool xok = ((unsigned)x < 1024u);
    float thr = thr_p[0];
    const float NEG = -__builtin_huge_valf();

    int jlo = jlo_t[zc], jhi = jhi_t[zc];
    int istart = jlo > 0 ? jlo - 1 : 0;
    int iend = (jhi + 2 < 50) ? jhi + 2 : 50;

    float gprev[10], A[8], B[8], Dprev[8], acc[10];
#pragma unroll
    for (int k = 0; k < 10; ++k) { gprev[k] = 0.f; acc[k] = 0.f; }
#pragma unroll
    for (int k = 0; k < 8; ++k) { A[k] = NEG; B[k] = NEG; Dprev[k] = 0.f; }

    // prologue: scale istart params + preload group 0
    const _Float16* plane = tmpHh + ((size_t)istart << 20);
    int r0 = rarr[istart];
    int gy0 = y0u - 1 - r0;
    int mcount = ((2 * r0 + 25) >> 4) << 4;          // >= 2r+10, mult of 16
    float vA[8], vB[8];
    LOADG(vA, 0);

    for (int i = istart; i <= iend; ++i) {
        const float* __restrict__ w = wp + i * WPSTRIDE;   // this scale's taps
        int mc = mcount;
        int m = 0;
        for (; m + 16 < mc; m += 16) {
            LOADG(vB, m + 8); FMAG(w, vA, m);
            LOADG(vA, m + 16); FMAG(w, vB, m + 8);
        }
        // tail pair (m == mc-16)
        LOADG(vB, m + 8);
        FMAG(w, vA, m);
        if (i < iend) {                   // prefetch next scale's group 0 into vA
            int rn = rarr[i + 1];
            plane = tmpHh + ((size_t)(i + 1) << 20);
            gy0 = y0u - 1 - rn;
            mcount = ((2 * rn + 25) >> 4) << 4;
            LOADG(vA, 0);
        }
        FMAG(w, vB, m + 8);
        // ---- epilogue for scale i (stores issue AFTER next-scale loads) ----
        if (i > istart) {
            int d = i - 1;
            float sg = sigmas[d];
#pragma unroll
            for (int k = 0; k < 10; ++k) {           // DoG; -inf outside image
                int gy = y0u - 1 + k;
                bool ok = xok && ((unsigned)gy < 1024u);
                gprev[k] = ok ? (gprev[k] - acc[k]) * sg : NEG;
            }
            float ym[8];
#pragma unroll
            for (int k = 0; k < 8; ++k)
                ym[k] = fmaxf(fmaxf(gprev[k], gprev[k + 1]), gprev[k + 2]);
            if (d - 1 >= jlo) {                      // emit j = d-1
                float pooled[8];
#pragma unroll
                for (int k = 0; k < 8; ++k) {
                    float pn = fmaxf(B[k], ym[k]);
                    float l  = __shfl_up(pn, 1);
                    float rr = __shfl_down(pn, 1);
                    pooled[k] = fmaxf(fmaxf(l, rr), pn);
                }
                if (xok && lane >= 1 && lane <= 62) {
                    int j = d - 1;
#pragma unroll
                    for (int k = 0; k < 8; ++k) {
                        float lm = fmaxf(pooled[k] + thr, 0.f);
                        float sm = 1.f - lm + Dprev[k] + thr;
                        float* orow = out + (((size_t)j << 20)
                                     + ((size_t)(y0u + k) << 10));
                        __builtin_nontemporal_store(lm, orow + x);
                        __builtin_nontemporal_store(sm, orow + DOG_ELEMS + x);
                    }
                }
            }
#pragma unroll
            for (int k = 0; k < 8; ++k) {
                B[k] = fmaxf(A[k], ym[k]);
                A[k] = ym[k];
                Dprev[k] = gprev[k + 1];             // dog center rows
            }
        }
#pragma unroll
        for (int k = 0; k < 10; ++k) { gprev[k] = acc[k]; acc[k] = 0.f; }
    }
    if (jhi == 49) {                                 // tail: j=49 (ym_50 = -inf)
        float pooled[8];
#pragma unroll
        for (int k = 0; k < 8; ++k) {
            float pn = B[k];
            float l  = __shfl_up(pn, 1);
            float rr = __shfl_down(pn, 1);
            pooled[k] = fmaxf(fmaxf(l, rr), pn);
        }
        if (xok && lane >= 1 && lane <= 62) {
#pragma unroll
            for (int k = 0; k < 8; ++k) {
                float lm = fmaxf(pooled[k] + thr, 0.f);
                float sm = 1.f - lm + Dprev[k] + thr;
                float* orow = out + (((size_t)49 << 20)
                             + ((size_t)(y0u + k) << 10));
                __builtin_nontemporal_store(lm, orow + x);
                __builtin_nontemporal_store(sm, orow + DOG_ELEMS + x);
            }
        }
    }
}

extern "C" void kernel_launch(void* const* d_in, const int* in_sizes, int n_in,
                              void* d_out, int out_size, void* d_ws, size_t ws_size,
                              hipStream_t stream) {
    const float* input  = (const float*)d_in[0];
    const float* weight = (const float*)d_in[1];
    const float* sigmas = (const float*)d_in[2];
    const float* thr    = (const float*)d_in[3];
    float* out = (float*)d_out;

    int S = 103;
    if (n_in > 1 && in_sizes[1] >= NS) {
        int s2 = in_sizes[1] / NS;
        S = (int)(sqrt((double)s2) + 0.5);
    }

    size_t need = (size_t)NS * PLANE * 2 + (size_t)NS * WPSTRIDE * 4
                + 64 * 4 + 1024 * 2 + 256;
    if (ws_size < need) return;   // insufficient scratch -> visible validation failure

    _Float16* tmpHh = (_Float16*)d_ws;                      // 51 fp16 planes (107 MB)
    float* wp   = (float*)((char*)d_ws + (size_t)NS * PLANE * 2);
    int*   rarr = (int*)(wp + NS * WPSTRIDE);               // 51 ints (64 slots)
    _Float16* zrowh = (_Float16*)(rarr + 64);               // 1024 fp16 zeros

    dog_prep <<<NS, 128, 0, stream>>>(weight, wp, rarr, zrowh, S);
    dog_hblur<<<dim3(512, 5), 256, 0, stream>>>(input, tmpHh, wp, rarr);
    dog_fused<<<11264, 64, 0, stream>>>(tmpHh, out, wp, rarr, sigmas, thr, zrowh);
}

// Round 10
// 502.334 us; speedup vs baseline: 1.3945x; 1.3945x over previous
//
#include <hip/hip_runtime.h>
#include <cmath>

#define NS 51
#define ND 50
#define PLANE 1048576            // 1024*1024
#define DOG_ELEMS (ND * PLANE)   // 52428800
#define WPSTRIDE 160             // padded 1-D kernel: 17 zeros | taps | zeros

// ---------------- K0: extract normalized 1-D kernels + radii; zero the zrow -----
__global__ void dog_prep(const float* __restrict__ weight,
                         float* __restrict__ wp,
                         int* __restrict__ rarr,
                         float* __restrict__ zrow, int S) {
    int i = blockIdx.x;
    int t = threadIdx.x;
    int R = (S - 1) >> 1;
    const float* row = weight + ((size_t)i * S + R) * S;   // center row of scale i
    __shared__ float sr[128];
    __shared__ float ssum;
    __shared__ int spad;
    if (t < S) sr[t] = row[t];
    for (int j = t; j < WPSTRIDE; j += blockDim.x) wp[i * WPSTRIDE + j] = 0.f;
    if (i == 0)
        for (int j = t; j < 1024; j += blockDim.x) zrow[j] = 0.f;
    __syncthreads();
    if (t == 0) {
        float sum = 0.f;
        for (int j = 0; j < S; ++j) sum += sr[j];
        int pad = 0;
        while (pad < R && sr[pad] == 0.f) ++pad;
        ssum = sum; spad = pad;
        rarr[i] = R - pad;
    }
    __syncthreads();
    int pad = spad;
    int r = R - pad;
    float inv = 1.f / ssum;
    for (int j = t; j <= 2 * r; j += blockDim.x)
        wp[i * WPSTRIDE + 17 + j] = sr[pad + j] * inv;
}

// ---------------- K1: horizontal blur, scale-chunked (unchanged from R8) --------
__global__ __launch_bounds__(256) void dog_hblur(
        const float* __restrict__ in, float* __restrict__ tmpH,
        const float* __restrict__ wp, const int* __restrict__ rarr) {
    const int lo_t[5] = {0, 17, 28, 37, 44};
    const int hi_t[5] = {17, 28, 37, 44, 51};
    int t = threadIdx.x;
    int grp = t >> 7;
    int tl = t & 127;
    int y = (blockIdx.x << 1) | grp;
    int zc = blockIdx.y;
    __shared__ float srow[2][1144];                 // 8 phases x 143
    const float* inrow = in + ((size_t)y << 10);
    for (int e = tl; e < 286; e += 128) {           // 286 float4 = x in [-56,1088)
        int xg = (e << 2) - 56;
        float4 v = make_float4(0.f, 0.f, 0.f, 0.f);
        if (xg >= 0 && xg < 1024) v = *(const float4*)(inrow + xg);
        float vv[4] = {v.x, v.y, v.z, v.w};
        int j = e << 2;
#pragma unroll
        for (int c = 0; c < 4; ++c) {
            int jj = j + c;
            srow[grp][(jj & 7) * 143 + (jj >> 3)] = vv[c];
        }
    }
    __syncthreads();
    const float* s = srow[grp];
    for (int i = lo_t[zc]; i < hi_t[zc]; ++i) {
        int r = rarr[i];
        const float* __restrict__ w = wp + i * WPSTRIDE;
        float acc[8];
#pragma unroll
        for (int k = 0; k < 8; ++k) acc[k] = 0.f;
        int c0 = 56 - r;
        int mcount = ((2 * r + 15) >> 3) << 3;      // >= 2r+8
        for (int m = 0; m < mcount; m += 8) {
            float v[8];
#pragma unroll
            for (int j2 = 0; j2 < 8; ++j2) {
                int q = m + j2 + c0;                // uniform
                v[j2] = s[(q & 7) * 143 + tl + (q >> 3)];
            }
#pragma unroll
            for (int j2 = 0; j2 < 8; ++j2)
#pragma unroll
                for (int k = 0; k < 8; ++k)
                    acc[k] = fmaf(w[17 + m + j2 - k], v[j2], acc[k]);
        }
        float* o = tmpH + (((size_t)i) << 20) + ((size_t)y << 10) + (tl << 3);
        *(float4*)o       = make_float4(acc[0], acc[1], acc[2], acc[3]);
        *(float4*)(o + 4) = make_float4(acc[4], acc[5], acc[6], acc[7]);
    }
}

// ---------------- K2: fused vconv + DoG + 3x3x3 pool + epilogue -----------------
// R8 geometry (256 thr / 4 waves, fp32 tmpH, XCD strip swizzle, pipelined vA/vB
// m-loop, nt stores). ONE change vs R8: cross-scale load-before-store reorder —
// next scale's group-0 loads issue BEFORE this scale's tail FMA + emit stores,
// so vmcnt waits (issue-order retire) never sit behind the 16 nt HBM stores.

#define LOADG(V, MM) do { int gyb_ = gy0 + (MM);                                  \
_Pragma("unroll")                                                                 \
    for (int j_ = 0; j_ < 8; ++j_) {                                              \
        int gy_ = gyb_ + j_;                                                      \
        const float* rp_ = ((unsigned)gy_ < 1024u)                                \
                         ? (plane + ((size_t)gy_ << 10)) : zrow;                  \
        V[j_] = rp_[xi];                                                          \
    } } while (0)

#define FMAG(W, V, MM) do {                                                       \
_Pragma("unroll")                                                                 \
    for (int j_ = 0; j_ < 8; ++j_)                                                \
_Pragma("unroll")                                                                 \
        for (int k_ = 0; k_ < 10; ++k_)                                           \
            acc[k_] = fmaf((W)[17 + (MM) + j_ - k_], V[j_], acc[k_]);             \
    } while (0)

__global__ __launch_bounds__(256, 4) void dog_fused(
        const float* __restrict__ tmpH, float* __restrict__ out,
        const float* __restrict__ wp, const int* __restrict__ rarr,
        const float* __restrict__ sigmas, const float* __restrict__ thr_p,
        const float* __restrict__ zrow) {
    const int jlo_t[5] = {0, 17, 28, 37, 44};
    const int jhi_t[5] = {16, 27, 36, 43, 49};
    // ---- XCD-aware swizzle: p%8 = XCD (dispatch round-robin). combo = strip id.
    int p = blockIdx.x;                   // 0..2815
    int xcd = p & 7;
    int s = p >> 3;                       // 0..351
    int k2 = s >> 5;                      // 0..10
    int ybg = s & 31;                     // 0..31  (same-XCD consecutive y-blocks)
    int combo = (k2 << 3) | xcd;          // 0..87
    if (combo >= 85) return;              // pad blocks
    int wx = combo % 17;                  // 0..16
    int zc = combo / 17;                  // 0..4
    int t = threadIdx.x;
    int lane = t & 63;
    int wv = t >> 6;
    int y0 = ((ybg << 2) | wv) << 3;      // 0..1016, step 8
    int y0u = __builtin_amdgcn_readfirstlane(y0);
    int x = wx * 62 - 1 + lane;           // -1 .. 1054
    int xi = min(max(x, 0), 1023);
    bool xok = ((unsigned)x < 1024u);
    float thr = thr_p[0];
    const float NEG = -__builtin_huge_valf();

    int jlo = jlo_t[zc], jhi = jhi_t[zc];
    int istart = jlo > 0 ? jlo - 1 : 0;
    int iend = (jhi + 2 < 50) ? jhi + 2 : 50;

    float gprev[10], A[8], B[8], Dprev[8], acc[10];
#pragma unroll
    for (int k = 0; k < 10; ++k) { gprev[k] = 0.f; acc[k] = 0.f; }
#pragma unroll
    for (int k = 0; k < 8; ++k) { A[k] = NEG; B[k] = NEG; Dprev[k] = 0.f; }

    // prologue: scale istart params + preload group 0
    const float* plane = tmpH + ((size_t)istart << 20);
    int r0 = rarr[istart];
    int gy0 = y0u - 1 - r0;
    int mcount = ((2 * r0 + 25) >> 4) << 4;          // >= 2r+10, mult of 16
    float vA[8], vB[8];
    LOADG(vA, 0);

    for (int i = istart; i <= iend; ++i) {
        const float* __restrict__ w = wp + i * WPSTRIDE;   // this scale's taps
        int mc = mcount;
        int m = 0;
        for (; m + 16 < mc; m += 16) {
            LOADG(vB, m + 8); FMAG(w, vA, m);
            LOADG(vA, m + 16); FMAG(w, vB, m + 8);
        }
        // tail pair (m == mc-16)
        LOADG(vB, m + 8);
        FMAG(w, vA, m);
        if (i < iend) {                   // prefetch next scale's group 0 into vA
            int rn = rarr[i + 1];
            plane = tmpH + ((size_t)(i + 1) << 20);
            gy0 = y0u - 1 - rn;
            mcount = ((2 * rn + 25) >> 4) << 4;
            LOADG(vA, 0);                 // issued BEFORE epilogue stores
        }
        FMAG(w, vB, m + 8);
        // ---- epilogue for scale i (stores issue AFTER next-scale loads) ----
        if (i > istart) {
            int d = i - 1;
            float sg = sigmas[d];
#pragma unroll
            for (int k = 0; k < 10; ++k) {           // DoG; -inf outside image
                int gy = y0u - 1 + k;
                bool ok = xok && ((unsigned)gy < 1024u);
                gprev[k] = ok ? (gprev[k] - acc[k]) * sg : NEG;
            }
            float ym[8];
#pragma unroll
            for (int k = 0; k < 8; ++k)
                ym[k] = fmaxf(fmaxf(gprev[k], gprev[k + 1]), gprev[k + 2]);
            if (d - 1 >= jlo) {                      // emit j = d-1
                float pooled[8];
#pragma unroll
                for (int k = 0; k < 8; ++k) {
                    float pn = fmaxf(B[k], ym[k]);
                    float l  = __shfl_up(pn, 1);
                    float rr = __shfl_down(pn, 1);
                    pooled[k] = fmaxf(fmaxf(l, rr), pn);
                }
                if (xok && lane >= 1 && lane <= 62) {
                    int j = d - 1;
#pragma unroll
                    for (int k = 0; k < 8; ++k) {
                        float lm = fmaxf(pooled[k] + thr, 0.f);
                        float sm = 1.f - lm + Dprev[k] + thr;
                        float* orow = out + (((size_t)j << 20)
                                     + ((size_t)(y0u + k) << 10));
                        __builtin_nontemporal_store(lm, orow + x);
                        __builtin_nontemporal_store(sm, orow + DOG_ELEMS + x);
                    }
                }
            }
#pragma unroll
            for (int k = 0; k < 8; ++k) {
                B[k] = fmaxf(A[k], ym[k]);
                A[k] = ym[k];
                Dprev[k] = gprev[k + 1];             // dog center rows
            }
        }
#pragma unroll
        for (int k = 0; k < 10; ++k) { gprev[k] = acc[k]; acc[k] = 0.f; }
    }
    if (jhi == 49) {                                 // tail: j=49 (ym_50 = -inf)
        float pooled[8];
#pragma unroll
        for (int k = 0; k < 8; ++k) {
            float pn = B[k];
            float l  = __shfl_up(pn, 1);
            float rr = __shfl_down(pn, 1);
            pooled[k] = fmaxf(fmaxf(l, rr), pn);
        }
        if (xok && lane >= 1 && lane <= 62) {
#pragma unroll
            for (int k = 0; k < 8; ++k) {
                float lm = fmaxf(pooled[k] + thr, 0.f);
                float sm = 1.f - lm + Dprev[k] + thr;
                float* orow = out + (((size_t)49 << 20)
                             + ((size_t)(y0u + k) << 10));
                __builtin_nontemporal_store(lm, orow + x);
                __builtin_nontemporal_store(sm, orow + DOG_ELEMS + x);
            }
        }
    }
}

extern "C" void kernel_launch(void* const* d_in, const int* in_sizes, int n_in,
                              void* d_out, int out_size, void* d_ws, size_t ws_size,
                              hipStream_t stream) {
    const float* input  = (const float*)d_in[0];
    const float* weight = (const float*)d_in[1];
    const float* sigmas = (const float*)d_in[2];
    const float* thr    = (const float*)d_in[3];
    float* out = (float*)d_out;

    int S = 103;
    if (n_in > 1 && in_sizes[1] >= NS) {
        int s2 = in_sizes[1] / NS;
        S = (int)(sqrt((double)s2) + 0.5);
    }

    size_t need = ((size_t)NS * PLANE + NS * WPSTRIDE + 64 + 1024) * 4 + 256;
    if (ws_size < need) return;   // insufficient scratch -> visible validation failure

    float* tmpH = (float*)d_ws;                    // 51 planes (214 MB)
    float* wp   = tmpH + (size_t)NS * PLANE;       // 51 * 160 floats
    int*   rarr = (int*)(wp + NS * WPSTRIDE);      // 51 ints (64 slots)
    float* zrow = (float*)(rarr + 64);             // 1024 zero floats

    dog_prep <<<NS, 128, 0, stream>>>(weight, wp, rarr, zrow, S);
    dog_hblur<<<dim3(512, 5), 256, 0, stream>>>(input, tmpH, wp, rarr);
    dog_fused<<<2816, 256, 0, stream>>>(tmpH, out, wp, rarr, sigmas, thr, zrow);
}